// Round 9
// baseline (1599.858 us; speedup 1.0000x reference)
//
#include <hip/hip_runtime.h>

// Sqrtm via the reference's coupled iteration, B=256, D=256, iterN=5.
// Round 14: single cooperative dispatch running all 12 GEMM steps with
// PER-MATRIX 4-block spin barriers (monotonic counter, relaxed agent
// atomics). Removes 11 device-wide joins + 12 launch ramps; matrices
// de-phase so CU-level stage bursts decorrelate (HBM duty up).
// The GEMM body is round-11's proven code (62us/GEMM, 689us total),
// unchanged: gload16 staging + XOR swizzle, 3-MFMA bf16 hi/lo product,
// T-step 1.5*W fold from B-LDS, scalar epilogues, XCD-pinned mapping.
// Coherence design (no __threadfence -- round-7's L2-flush disaster):
//  - all 4 blocks of a matrix are pinned to ONE XCD -> producer stores
//    land in the shared XCD L2; __syncthreads() drains vmcnt(0) first.
//  - readers bypass possibly-stale vL1 via global_load_lds aux=SC0.
//  - flag adds/spins are relaxed agent atomics (no cache maintenance).
//  - counter zeroed by an init dispatch each launch (graph-replay safe).
// Co-residency (spin-safety) guaranteed by hipLaunchCooperativeKernel;
// on ANY launch error we fall back to the proven round-11 12-dispatch
// chain in the same kernel_launch call.
//
// Storage: fp32 emulated as 2-term bf16 planes (hi+lo), product via 3 MFMA:
//   A@B ~= Ah@Bh + Al@Bh + Ah@Bl
// All iterates are symmetric polynomials in A => C = A@B^T == A@B, so both
// operands are read as [outer][k] rows (no transposition anywhere).
//
// Chain (A planes live in d_out, dead before the final fp32 overwrite):
//   Z1 = 1.5I - 0.5A
//   3x:  W = A@Z ; T = 1.5W - 0.5(Z@W) ; Z' = T@Z
//   fin: W = A@Z ; T = 1.5W - 0.5(Z@W) [A=Z,B=W] ; out = sqrt(normA)*(T@W)

#define DD 256
#define PLN 65536   // shorts per bf16 plane
#define MATN 65536  // floats per fp32 matrix
#define NBT 256

typedef short s16x8 __attribute__((ext_vector_type(8)));
typedef short s16x4 __attribute__((ext_vector_type(4)));
typedef float f32x4 __attribute__((ext_vector_type(4)));

__device__ __forceinline__ short bf16rtn(float f) {
    unsigned u = __float_as_uint(f);
    u += 0x7FFFu + ((u >> 16) & 1u);   // round-to-nearest-even
    return (short)(u >> 16);
}
__device__ __forceinline__ float bf16tof(short h) {
    return __uint_as_float(((unsigned)(unsigned short)h) << 16);
}

__device__ __forceinline__ void gload16(const short* g, short* l) {
    __builtin_amdgcn_global_load_lds(
        (const __attribute__((address_space(1))) void*)g,
        (__attribute__((address_space(3))) void*)l, 16, 0, 0);
}
// SC0 (L1-bypass) variant for the fused kernel's intra-kernel RAW reads.
__device__ __forceinline__ void gload16c(const short* g, short* l) {
    __builtin_amdgcn_global_load_lds(
        (const __attribute__((address_space(1))) void*)g,
        (__attribute__((address_space(3))) void*)l, 16, 0, 1);
}

// ---- setup: sc[lb]=sqrt(normA); X planes = split(invN*x); Z1 planes ----
__global__ __launch_bounds__(256) void setup_kernel(
    const float* __restrict__ x,
    short* __restrict__ zbase, int zstride,
    short* __restrict__ xbase, int xstride,
    float* __restrict__ sc)
{
    const int lb = blockIdx.x, tid = threadIdx.x;
    const float* X = x + (size_t)lb * MATN;
    short* Zh = zbase + (size_t)lb * zstride;  short* Zl = Zh + PLN;
    short* Xh = xbase + (size_t)lb * xstride;  short* Xl = Xh + PLN;
    __shared__ float red[4];
    __shared__ float sInv;

    float s = 0.f;
    for (int i = 0; i < 64; ++i) {
        const float4 v = *(const float4*)(X + ((i * 256 + tid) << 2));
        s += v.x + v.y + v.z + v.w;
    }
    for (int o = 32; o; o >>= 1) s += __shfl_down(s, o, 64);
    if ((tid & 63) == 0) red[tid >> 6] = s;
    __syncthreads();
    if (tid == 0) {
        const float t = red[0] + red[1] + red[2] + red[3];
        sc[lb] = sqrtf(t);
        sInv = 1.f / t;
    }
    __syncthreads();
    const float invN = sInv;

    for (int i = 0; i < 64; ++i) {
        const int e = (i * 256 + tid) << 2;
        const int r = e >> 8, c = e & 255;
        const float4 v = *(const float4*)(X + e);
        const float a0 = invN * v.x, a1 = invN * v.y,
                    a2 = invN * v.z, a3 = invN * v.w;
        s16x4 xh, xl, zh, zl;
        xh[0] = bf16rtn(a0); xl[0] = bf16rtn(a0 - bf16tof(xh[0]));
        xh[1] = bf16rtn(a1); xl[1] = bf16rtn(a1 - bf16tof(xh[1]));
        xh[2] = bf16rtn(a2); xl[2] = bf16rtn(a2 - bf16tof(xh[2]));
        xh[3] = bf16rtn(a3); xl[3] = bf16rtn(a3 - bf16tof(xh[3]));
        const float z0 = ((r == c + 0) ? 1.5f : 0.f) - 0.5f * a0;
        const float z1 = ((r == c + 1) ? 1.5f : 0.f) - 0.5f * a1;
        const float z2 = ((r == c + 2) ? 1.5f : 0.f) - 0.5f * a2;
        const float z3 = ((r == c + 3) ? 1.5f : 0.f) - 0.5f * a3;
        zh[0] = bf16rtn(z0); zl[0] = bf16rtn(z0 - bf16tof(zh[0]));
        zh[1] = bf16rtn(z1); zl[1] = bf16rtn(z1 - bf16tof(zh[1]));
        zh[2] = bf16rtn(z2); zl[2] = bf16rtn(z2 - bf16tof(zh[2]));
        zh[3] = bf16rtn(z3); zl[3] = bf16rtn(z3 - bf16tof(zh[3]));
        *(s16x4*)(Xh + e) = xh; *(s16x4*)(Xl + e) = xl;
        *(s16x4*)(Zh + e) = zh; *(s16x4*)(Zl + e) = zl;
    }
}

__global__ void init_cnt(unsigned* cnt) { cnt[threadIdx.x] = 0u; }

// ================= fused cooperative chain kernel =================
// grid = 1024: xcd = bid&7, s = bid>>3, lb = xcd*32 + s/4, tile = s&3.
__global__ __launch_bounds__(256, 4) void fused_chain(
    const float* __restrict__ x, float* __restrict__ out,
    short* __restrict__ ws, float* __restrict__ sc,
    unsigned* __restrict__ cnt)
{
    __shared__ __align__(16) short sAh[4096];
    __shared__ __align__(16) short sAl[4096];
    __shared__ __align__(16) short sBh[4096];
    __shared__ __align__(16) short sBl[4096];

    const int bid = blockIdx.x;
    const int xcd = bid & 7, s = bid >> 3;
    const int lb = xcd * 32 + (s >> 2);
    const int t = s & 3;
    const int tileR = (t >> 1) << 7, tileC = (t & 1) << 7;
    const int tid = threadIdx.x, lane = tid & 63, wave = tid >> 6;
    const int wr = wave >> 1, wc = wave & 1, ln = lane & 15, quad = lane >> 4;

    short* S0 = ws + (size_t)lb * (6 * (size_t)PLN);
    short* Xp = (short*)out + (size_t)lb * (2 * (size_t)PLN);
    float* O = out + (size_t)lb * MATN;

    // staging coords (round-11): 4 threads (16B each) per row
    const int srow = tid >> 2;
    const int gs = (tid & 3) ^ ((tid >> 3) & 3);
    const size_t aoff0 = (size_t)(tileR + srow) * DD + gs * 8;
    const size_t aoff1 = aoff0 + (size_t)64 * DD;
    const size_t boff0 = (size_t)(tileC + srow) * DD + gs * 8;
    const size_t boff1 = boff0 + (size_t)64 * DD;
    const int ldo0 = wave * 512;
    const int ldo1 = 2048 + wave * 512;
    const int fo = ((quad ^ ((ln >> 1) & 3)) << 3);

    // step tables, bit-packed (slots: 0..2 = ws, 3 = A planes in d_out)
    constexpr unsigned SAp = 3u | (0u<<2) | (2u<<4) | (3u<<6) | (1u<<8) | (2u<<10)
                           | (3u<<12) | (0u<<14) | (2u<<16) | (3u<<18) | (1u<<20) | (2u<<22);
    constexpr unsigned SBp = 0u | (1u<<2) | (0u<<4) | (1u<<6) | (0u<<8) | (1u<<10)
                           | (0u<<12) | (1u<<14) | (0u<<16) | (1u<<18) | (0u<<20) | (0u<<22);
    constexpr unsigned SCp = 1u | (2u<<2) | (1u<<4) | (0u<<6) | (2u<<8) | (0u<<10)
                           | (1u<<12) | (2u<<14) | (1u<<16) | (0u<<18) | (2u<<20);
    constexpr unsigned FDm = (1u<<1) | (1u<<4) | (1u<<7) | (1u<<10);

#pragma unroll 1
    for (int st = 0; st < 12; ++st) {
        const int sa = (SAp >> (2 * st)) & 3;
        const int sb = (SBp >> (2 * st)) & 3;
        const int scs = (SCp >> (2 * st)) & 3;
        const int fold = (FDm >> st) & 1;
        const short* Ah = (sa == 3) ? Xp : S0 + (size_t)sa * (2 * (size_t)PLN);
        const short* Bh = (sb == 3) ? Xp : S0 + (size_t)sb * (2 * (size_t)PLN);
        const short* Al = Ah + PLN;
        const short* Bl = Bh + PLN;

        f32x4 acc[4][4];
#pragma unroll
        for (int i = 0; i < 4; ++i)
#pragma unroll
            for (int j = 0; j < 4; ++j) {
                acc[i][j][0] = 0.f; acc[i][j][1] = 0.f;
                acc[i][j][2] = 0.f; acc[i][j][3] = 0.f;
            }

        for (int kt = 0; kt < DD; kt += 32) {
            __syncthreads();
            gload16c(Ah + aoff0 + kt, sAh + ldo0);
            gload16c(Ah + aoff1 + kt, sAh + ldo1);
            gload16c(Al + aoff0 + kt, sAl + ldo0);
            gload16c(Al + aoff1 + kt, sAl + ldo1);
            gload16c(Bh + boff0 + kt, sBh + ldo0);
            gload16c(Bh + boff1 + kt, sBh + ldo1);
            gload16c(Bl + boff0 + kt, sBl + ldo0);
            gload16c(Bl + boff1 + kt, sBl + ldo1);
            __syncthreads();

            s16x8 ahf[4], alf[4];
#pragma unroll
            for (int i = 0; i < 4; ++i) {
                const int ro = (wr * 64 + i * 16 + ln) * 32 + fo;
                ahf[i] = *(const s16x8*)(sAh + ro);
                alf[i] = *(const s16x8*)(sAl + ro);
            }
#pragma unroll
            for (int j = 0; j < 4; ++j) {
                const int co = (wc * 64 + j * 16 + ln) * 32 + fo;
                const s16x8 bh = *(const s16x8*)(sBh + co);
                const s16x8 bl = *(const s16x8*)(sBl + co);
#pragma unroll
                for (int i = 0; i < 4; ++i) {
                    acc[i][j] = __builtin_amdgcn_mfma_f32_16x16x32_bf16(ahf[i], bh, acc[i][j], 0, 0, 0);
                    acc[i][j] = __builtin_amdgcn_mfma_f32_16x16x32_bf16(alf[i], bh, acc[i][j], 0, 0, 0);
                    acc[i][j] = __builtin_amdgcn_mfma_f32_16x16x32_bf16(ahf[i], bl, acc[i][j], 0, 0, 0);
                }
            }

            // fold 1.5*W from B-LDS (W symmetric; see round-11 derivation)
            if (fold) {
                const int base = kt - tileR - wr * 64;
                if (0 <= base && base < 64) {
#pragma unroll
                    for (int i = 0; i < 4; ++i) {
                        const int lr = i * 16 - base;
                        if (0 <= lr && lr < 32) {
#pragma unroll
                            for (int j = 0; j < 4; ++j) {
                                const int nc = wc * 64 + j * 16 + ln;
                                const int key = (nc >> 1) & 3;
#pragma unroll
                                for (int r = 0; r < 4; ++r) {
                                    const int kr = lr + quad * 4 + r;
                                    const int ph = nc * 32
                                        + (((kr >> 3) ^ key) << 3) + (kr & 7);
                                    const float w = bf16tof(sBh[ph])
                                                  + bf16tof(sBl[ph]);
                                    acc[i][j][r] = fmaf(-3.0f, w, acc[i][j][r]);
                                }
                            }
                        }
                    }
                }
            }
        }

        // epilogue (round-11 scalar stores)
        if (st == 11) {
            unsigned su = __hip_atomic_load((unsigned*)(sc + lb),
                                            __ATOMIC_RELAXED,
                                            __HIP_MEMORY_SCOPE_AGENT);
            const float alphav = __uint_as_float(su);
#pragma unroll
            for (int i = 0; i < 4; ++i)
#pragma unroll
                for (int j = 0; j < 4; ++j) {
                    const int col = tileC + wc * 64 + j * 16 + ln;
#pragma unroll
                    for (int r = 0; r < 4; ++r) {
                        const int row = tileR + wr * 64 + i * 16 + quad * 4 + r;
                        O[row * DD + col] = alphav * acc[i][j][r];
                    }
                }
        } else {
            const float alphav = fold ? -0.5f : 1.0f;
            short* Ch = (scs == 3) ? Xp : S0 + (size_t)scs * (2 * (size_t)PLN);
            short* Cl = Ch + PLN;
#pragma unroll
            for (int i = 0; i < 4; ++i)
#pragma unroll
                for (int j = 0; j < 4; ++j) {
                    const int col = tileC + wc * 64 + j * 16 + ln;
#pragma unroll
                    for (int r = 0; r < 4; ++r) {
                        const int row = tileR + wr * 64 + i * 16 + quad * 4 + r;
                        const int idx = row * DD + col;
                        const float v = alphav * acc[i][j][r];
                        const short h = bf16rtn(v);
                        Ch[idx] = h;
                        Cl[idx] = bf16rtn(v - bf16tof(h));
                    }
                }
        }

        // per-matrix barrier: stores drained at this barrier (vmcnt0), then
        // arrive; spin until all 4 tile-blocks of lb finished step st.
        __syncthreads();
        if (tid == 0)
            __hip_atomic_fetch_add(&cnt[lb], 1u, __ATOMIC_RELAXED,
                                   __HIP_MEMORY_SCOPE_AGENT);
        if (st < 11) {
            if (tid == 0) {
                const unsigned tgt = 4u * (unsigned)(st + 1);
                while (__hip_atomic_load(&cnt[lb], __ATOMIC_RELAXED,
                                         __HIP_MEMORY_SCOPE_AGENT) < tgt)
                    __builtin_amdgcn_s_sleep(8);
            }
            __syncthreads();
        }
    }
}

// ---- round-11 batched GEMM (fallback path), unchanged ----
__global__ __launch_bounds__(256) void gemm_ns(
    const short* Ahg, int astride,
    const short* Bhg, int bstride,
    short* __restrict__ Chg, int cstride,
    float* __restrict__ Cfg, int cfstride,
    const float* __restrict__ sc,
    float alpha, int fold, int usesc, int nmat, int swz)
{
    __shared__ __align__(16) short sAh[4096];
    __shared__ __align__(16) short sAl[4096];
    __shared__ __align__(16) short sBh[4096];
    __shared__ __align__(16) short sBl[4096];

    const int bid = blockIdx.x;
    int lb, t;
    if (swz) {
        const int xcd = bid & 7, s = bid >> 3;
        lb = xcd * (nmat >> 3) + (s >> 2);
        t = s & 3;
    } else {
        lb = bid >> 2;
        t = bid & 3;
    }
    const int tileR = (t >> 1) << 7, tileC = (t & 1) << 7;
    const int tid = threadIdx.x, lane = tid & 63, wave = tid >> 6;
    const int wr = wave >> 1, wc = wave & 1, ln = lane & 15, quad = lane >> 4;

    const short* Ah = Ahg + (size_t)lb * astride;  const short* Al = Ah + PLN;
    const short* Bh = Bhg + (size_t)lb * bstride;  const short* Bl = Bh + PLN;

    const int srow = tid >> 2;
    const int gs = (tid & 3) ^ ((tid >> 3) & 3);
    const size_t aoff0 = (size_t)(tileR + srow) * DD + gs * 8;
    const size_t aoff1 = aoff0 + (size_t)64 * DD;
    const size_t boff0 = (size_t)(tileC + srow) * DD + gs * 8;
    const size_t boff1 = boff0 + (size_t)64 * DD;
    const int ldo0 = wave * 512;
    const int ldo1 = 2048 + wave * 512;

    f32x4 acc[4][4];
#pragma unroll
    for (int i = 0; i < 4; ++i)
#pragma unroll
        for (int j = 0; j < 4; ++j) {
            acc[i][j][0] = 0.f; acc[i][j][1] = 0.f;
            acc[i][j][2] = 0.f; acc[i][j][3] = 0.f;
        }

    const int fo = ((quad ^ ((ln >> 1) & 3)) << 3);

    for (int kt = 0; kt < DD; kt += 32) {
        __syncthreads();
        gload16(Ah + aoff0 + kt, sAh + ldo0);
        gload16(Ah + aoff1 + kt, sAh + ldo1);
        gload16(Al + aoff0 + kt, sAl + ldo0);
        gload16(Al + aoff1 + kt, sAl + ldo1);
        gload16(Bh + boff0 + kt, sBh + ldo0);
        gload16(Bh + boff1 + kt, sBh + ldo1);
        gload16(Bl + boff0 + kt, sBl + ldo0);
        gload16(Bl + boff1 + kt, sBl + ldo1);
        __syncthreads();

        s16x8 ahf[4], alf[4];
#pragma unroll
        for (int i = 0; i < 4; ++i) {
            const int ro = (wr * 64 + i * 16 + ln) * 32 + fo;
            ahf[i] = *(const s16x8*)(sAh + ro);
            alf[i] = *(const s16x8*)(sAl + ro);
        }
#pragma unroll
        for (int j = 0; j < 4; ++j) {
            const int co = (wc * 64 + j * 16 + ln) * 32 + fo;
            const s16x8 bh = *(const s16x8*)(sBh + co);
            const s16x8 bl = *(const s16x8*)(sBl + co);
#pragma unroll
            for (int i = 0; i < 4; ++i) {
                acc[i][j] = __builtin_amdgcn_mfma_f32_16x16x32_bf16(ahf[i], bh, acc[i][j], 0, 0, 0);
                acc[i][j] = __builtin_amdgcn_mfma_f32_16x16x32_bf16(alf[i], bh, acc[i][j], 0, 0, 0);
                acc[i][j] = __builtin_amdgcn_mfma_f32_16x16x32_bf16(ahf[i], bl, acc[i][j], 0, 0, 0);
            }
        }

        if (fold) {
            const int base = kt - tileR - wr * 64;
            if (0 <= base && base < 64) {
#pragma unroll
                for (int i = 0; i < 4; ++i) {
                    const int lr = i * 16 - base;
                    if (0 <= lr && lr < 32) {
#pragma unroll
                        for (int j = 0; j < 4; ++j) {
                            const int nc = wc * 64 + j * 16 + ln;
                            const int key = (nc >> 1) & 3;
#pragma unroll
                            for (int r = 0; r < 4; ++r) {
                                const int kr = lr + quad * 4 + r;
                                const int ph = nc * 32
                                    + (((kr >> 3) ^ key) << 3) + (kr & 7);
                                const float w = bf16tof(sBh[ph])
                                              + bf16tof(sBl[ph]);
                                acc[i][j][r] = fmaf(-3.0f, w, acc[i][j][r]);
                            }
                        }
                    }
                }
            }
        }
    }

    const float alphav = usesc ? sc[lb] : alpha;
    if (Chg) {
        short* Ch = Chg + (size_t)lb * cstride;  short* Cl = Ch + PLN;
#pragma unroll
        for (int i = 0; i < 4; ++i)
#pragma unroll
            for (int j = 0; j < 4; ++j) {
                const int col = tileC + wc * 64 + j * 16 + ln;
#pragma unroll
                for (int r = 0; r < 4; ++r) {
                    const int row = tileR + wr * 64 + i * 16 + quad * 4 + r;
                    const int idx = row * DD + col;
                    const float v = alphav * acc[i][j][r];
                    const short h = bf16rtn(v);
                    Ch[idx] = h;
                    Cl[idx] = bf16rtn(v - bf16tof(h));
                }
            }
    } else {
        float* Cf = Cfg + (size_t)lb * cfstride;
#pragma unroll
        for (int i = 0; i < 4; ++i)
#pragma unroll
            for (int j = 0; j < 4; ++j) {
                const int col = tileC + wc * 64 + j * 16 + ln;
#pragma unroll
                for (int r = 0; r < 4; ++r) {
                    const int row = tileR + wr * 64 + i * 16 + quad * 4 + r;
                    Cf[row * DD + col] = alphav * acc[i][j][r];
                }
            }
    }
}

static void run_fallback_chain(const float* xs, float* os, short* base,
                               float* sc, int n, hipStream_t stream)
{
    const int ES = 6 * PLN;
    const int EX = 2 * PLN;
    const int swz = (n % 8 == 0) ? 1 : 0;
    short* XH = (short*)os;
    short* SA = base;
    short* SB = base + 2 * PLN;
    short* TT = base + 4 * PLN;
    const dim3 G(4 * n), T(256);

#define GEMM_B(AH, AS, BH, BS, CH, AL, FD) \
    gemm_ns<<<G, T, 0, stream>>>((AH), (AS), (BH), (BS), (CH), ES, \
                                 nullptr, 0, sc, (AL), (FD), 0, n, swz)
    GEMM_B(XH, EX, SA, ES, SB, 1.f, 0);
    GEMM_B(SA, ES, SB, ES, TT, -0.5f, 1);
    GEMM_B(TT, ES, SA, ES, SB, 1.f, 0);
    GEMM_B(XH, EX, SB, ES, SA, 1.f, 0);
    GEMM_B(SB, ES, SA, ES, TT, -0.5f, 1);
    GEMM_B(TT, ES, SB, ES, SA, 1.f, 0);
    GEMM_B(XH, EX, SA, ES, SB, 1.f, 0);
    GEMM_B(SA, ES, SB, ES, TT, -0.5f, 1);
    GEMM_B(TT, ES, SA, ES, SB, 1.f, 0);
    GEMM_B(XH, EX, SB, ES, SA, 1.f, 0);
    GEMM_B(SB, ES, SA, ES, TT, -0.5f, 1);
    gemm_ns<<<G, T, 0, stream>>>(TT, ES, SA, ES, nullptr, 0, os, MATN,
                                 sc, 0.f, 0, 1, n, swz);
#undef GEMM_B
}

extern "C" void kernel_launch(void* const* d_in, const int* in_sizes, int n_in,
                              void* d_out, int out_size, void* d_ws, size_t ws_size,
                              hipStream_t stream)
{
    const float* x = (const float*)d_in[0];
    float* out = (float*)d_out;

    // ws layout: [256 floats sc][256 u32 cnt][nbuf elems x 6 bf16 planes]
    float* sc = (float*)d_ws;
    unsigned* cnt = (unsigned*)(sc + 256);
    short* base = (short*)(sc + 512);
    long availsh = (long)(ws_size / 2) - 1024;
    int nbuf = (int)(availsh / (6L * PLN));
    if (nbuf > NBT) nbuf = NBT;
    if (nbuf < 1) nbuf = 1;
    const int ES = 6 * PLN;
    const int EX = 2 * PLN;

    if (nbuf >= NBT) {
        // single-chunk: setup + one cooperative fused dispatch
        init_cnt<<<1, 256, 0, stream>>>(cnt);
        setup_kernel<<<NBT, 256, 0, stream>>>(x, base, ES, (short*)out, EX, sc);

        const float* xa = x; float* oa = out; short* wa = base;
        float* sca = sc; unsigned* ca = cnt;
        void* kargs[] = {(void*)&xa, (void*)&oa, (void*)&wa,
                         (void*)&sca, (void*)&ca};
        hipError_t e = hipLaunchCooperativeKernel(
            (const void*)fused_chain, dim3(8 * 128), dim3(256), kargs, 0, stream);
        if (e != hipSuccess) {
            // fallback: proven round-11 12-dispatch chain
            run_fallback_chain(x, out, base, sc, NBT, stream);
        }
    } else {
        for (int c0 = 0; c0 < NBT; c0 += nbuf) {
            const int n = (NBT - c0 < nbuf) ? (NBT - c0) : nbuf;
            const float* xs = x + (size_t)c0 * MATN;
            float* os = out + (size_t)c0 * MATN;
            setup_kernel<<<n, 256, 0, stream>>>(xs, base, ES, (short*)os, EX, sc);
            run_fallback_chain(xs, os, base, sc, n, stream);
        }
    }
}